// Round 10
// baseline (404.219 us; speedup 1.0000x reference)
//
#include <hip/hip_runtime.h>
#include <hip/hip_bf16.h>

// CompressiveMemory.update() — B=65536, R=K=8, D=256, fp32.
// R9 structure (best: 388.9us) with ONE change (A/B): plain cached stores
// instead of nontemporal stores. Loads stay nontemporal (R8 A/B: nt >= cached).
//   k0 transpose_pack: W (o,i,k) fp32 -> Wt2b[m4][o][j] bf16 (m=i*2+k), 256KB ws.
//   k1 fused_update: 1 block/sample; wave w copies fm rows {w,w+4}, cm rows
//      {w,w+4} (MLP=4); shift blocks run per-wave barrier-free conv inline
//      with bf16 weights (block-uniform branch).

#define NB 65536
#define RR 8
#define KK 8
#define DD 256
#define WFLOATS (DD * DD * 2)

typedef float f4 __attribute__((ext_vector_type(4)));

static __device__ __forceinline__ f4 ntload(const float* p) {
    return __builtin_nontemporal_load((const f4*)p);
}
static __device__ __forceinline__ float bf2f(unsigned short u) {
    return __uint_as_float(((unsigned int)u) << 16);
}

__global__ __launch_bounds__(256) void transpose_pack(
    const float* __restrict__ W, unsigned short* __restrict__ Wt2b)
{
    int t = blockIdx.x * 256 + threadIdx.x;   // coalesced read of W
    int o = t >> 9;
    int m = t & 511;                          // m = i*2 + k
    __hip_bfloat16 h = __float2bfloat16(W[t]);
    Wt2b[(size_t)(m >> 2) * (DD * 4) + o * 4 + (m & 3)] = *(unsigned short*)&h;
}

__global__ __launch_bounds__(256) void fused_update(
    const float* __restrict__ fm,          // (B,R,D)
    const float* __restrict__ cm,          // (B,K,D)
    const int* __restrict__ cnt_in,
    const float* __restrict__ seg,         // (B,D)
    const int* __restrict__ valid,
    const unsigned short* __restrict__ Wt2b, // (128, 256, 4) bf16
    const float* __restrict__ bias,        // (256,)
    float* __restrict__ out_fm,
    float* __restrict__ out_cm,
    float* __restrict__ out_cnt)
{
    __shared__ float xbuf[4][512];         // per-wave slice: x[2i]=cm7[i], x[2i+1]=fm0[i]

    const int b    = blockIdx.x;
    const int tid  = threadIdx.x;
    const int w    = tid >> 6;             // 0..3
    const int lane = tid & 63;
    const int c    = lane << 2;

    const int  cnt = cnt_in[b];
    const bool v   = valid[b] != 0;
    const bool ins = v && (cnt < RR);
    const bool shf = v && (cnt >= RR);     // block-uniform

    const float* fmb  = fm  + (size_t)b * (RR * DD);
    const float* cmb  = cm  + (size_t)b * (KK * DD);
    const float* segb = seg + (size_t)b * DD;
    float* ofm = out_fm + (size_t)b * (RR * DD);
    float* ocm = out_cm + (size_t)b * (KK * DD);

    const int r0 = w, r1 = w + 4;

    // fm sources (wave-uniform selection)
    const float* f0src = shf ? fmb + (r0 + 1) * DD
                             : (ins && r0 == cnt) ? segb : fmb + r0 * DD;
    const float* f1src = shf ? ((r1 < 7) ? fmb + (r1 + 1) * DD : segb)
                             : (ins && r1 == cnt) ? segb : fmb + r1 * DD;
    // cm sources; shf && row==7 produced by inline conv below
    const bool   c1st  = !(shf && r1 == 7);
    const float* c0src = cmb + (shf ? r0 + 1 : r0) * DD;
    const float* c1src = c1st ? cmb + (shf ? r1 + 1 : r1) * DD : cmb;

    // issue all stream loads first (MLP=4) — nontemporal
    f4 a  = ntload(f0src + c);
    f4 bq = ntload(f1src + c);
    f4 d  = ntload(c0src + c);
    f4 e  = ntload(c1src + c);

    // plain cached stores (A/B vs R9's nontemporal)
    *(f4*)(ofm + r0 * DD + c) = a;
    *(f4*)(ofm + r1 * DD + c) = bq;
    *(f4*)(ocm + r0 * DD + c) = d;
    if (c1st) *(f4*)(ocm + r1 * DD + c) = e;

    if (tid == 0)
        out_cnt[b] = (float)(cnt + (ins ? 1 : 0));

    if (shf) {                              // block-uniform; conv is per-wave
        f4 cv = *(const f4*)(cmb + (KK - 1) * DD + c);
        f4 fv = *(const f4*)(fmb + c);
        f4 x0 = {cv.x, fv.x, cv.y, fv.y};
        f4 x1 = {cv.z, fv.z, cv.w, fv.w};
        *(f4*)&xbuf[w][2 * c]     = x0;
        *(f4*)&xbuf[w][2 * c + 4] = x1;
        // wave-internal LDS dep -> compiler emits lgkmcnt wait; no __syncthreads

        const int o = (w << 6) + lane;      // wave w owns channels 64w..64w+63
        float acc = 0.f;
        const unsigned short* wp = Wt2b + o * 4;
        #pragma unroll 8
        for (int m4 = 0; m4 < 128; ++m4) {
            const ushort4 wq = *(const ushort4*)(wp + (size_t)m4 * (DD * 4)); // 512B/wave, L2-hot
            const f4 xq = *(const f4*)&xbuf[w][m4 * 4];                       // uniform -> broadcast
            acc += xq.x * bf2f(wq.x) + xq.y * bf2f(wq.y)
                 + xq.z * bf2f(wq.z) + xq.w * bf2f(wq.w);
        }
        acc += bias[o];
        ocm[(KK - 1) * DD + o] = acc;       // 256B/wave coalesced
    }
}

extern "C" void kernel_launch(void* const* d_in, const int* in_sizes, int n_in,
                              void* d_out, int out_size, void* d_ws, size_t ws_size,
                              hipStream_t stream) {
    const float* fm    = (const float*)d_in[0];
    const float* cm    = (const float*)d_in[1];
    const int*   cnt   = (const int*)d_in[2];
    const float* seg   = (const float*)d_in[3];
    const int*   valid = (const int*)d_in[4];
    const float* W     = (const float*)d_in[5];
    const float* bias  = (const float*)d_in[6];

    float* out_fm  = (float*)d_out;
    float* out_cm  = out_fm + (size_t)NB * RR * DD;
    float* out_cnt = out_cm + (size_t)NB * KK * DD;

    unsigned short* Wt2b = (unsigned short*)d_ws;   // 256KB

    hipLaunchKernelGGL(transpose_pack, dim3(WFLOATS / 256), dim3(256), 0, stream, W, Wt2b);
    hipLaunchKernelGGL(fused_update, dim3(NB), dim3(256), 0, stream,
                       fm, cm, cnt, seg, valid, Wt2b, bias, out_fm, out_cm, out_cnt);
}

// Round 11
// 387.013 us; speedup vs baseline: 1.0445x; 1.0445x over previous
//
#include <hip/hip_runtime.h>
#include <hip/hip_bf16.h>

// CompressiveMemory.update() — B=65536, R=K=8, D=256, fp32.
// R9 structure == best measured (388.9us). Exact revert of R10's store change.
// Policy (both A/B'd): nontemporal LOADS (R8: nt 417.4 < cached 422.1) and
// nontemporal STORES (R10: nt 388.9 < cached 404.2).
//   k0 transpose_pack: W (o,i,k) fp32 -> Wt2b[m4][o][j] bf16 (m=i*2+k), 256KB ws.
//   k1 fused_update: 1 block/sample; wave w copies fm rows {w,w+4}, cm rows
//      {w,w+4} (MLP=4); shift blocks run per-wave barrier-free conv inline
//      with bf16 weights (block-uniform branch).

#define NB 65536
#define RR 8
#define KK 8
#define DD 256
#define WFLOATS (DD * DD * 2)

typedef float f4 __attribute__((ext_vector_type(4)));

static __device__ __forceinline__ f4 ntload(const float* p) {
    return __builtin_nontemporal_load((const f4*)p);
}
static __device__ __forceinline__ void ntstore(float* p, f4 v) {
    __builtin_nontemporal_store(v, (f4*)p);
}
static __device__ __forceinline__ float bf2f(unsigned short u) {
    return __uint_as_float(((unsigned int)u) << 16);
}

__global__ __launch_bounds__(256) void transpose_pack(
    const float* __restrict__ W, unsigned short* __restrict__ Wt2b)
{
    int t = blockIdx.x * 256 + threadIdx.x;   // coalesced read of W
    int o = t >> 9;
    int m = t & 511;                          // m = i*2 + k
    __hip_bfloat16 h = __float2bfloat16(W[t]);
    Wt2b[(size_t)(m >> 2) * (DD * 4) + o * 4 + (m & 3)] = *(unsigned short*)&h;
}

__global__ __launch_bounds__(256) void fused_update(
    const float* __restrict__ fm,          // (B,R,D)
    const float* __restrict__ cm,          // (B,K,D)
    const int* __restrict__ cnt_in,
    const float* __restrict__ seg,         // (B,D)
    const int* __restrict__ valid,
    const unsigned short* __restrict__ Wt2b, // (128, 256, 4) bf16
    const float* __restrict__ bias,        // (256,)
    float* __restrict__ out_fm,
    float* __restrict__ out_cm,
    float* __restrict__ out_cnt)
{
    __shared__ float xbuf[4][512];         // per-wave slice: x[2i]=cm7[i], x[2i+1]=fm0[i]

    const int b    = blockIdx.x;
    const int tid  = threadIdx.x;
    const int w    = tid >> 6;             // 0..3
    const int lane = tid & 63;
    const int c    = lane << 2;

    const int  cnt = cnt_in[b];
    const bool v   = valid[b] != 0;
    const bool ins = v && (cnt < RR);
    const bool shf = v && (cnt >= RR);     // block-uniform

    const float* fmb  = fm  + (size_t)b * (RR * DD);
    const float* cmb  = cm  + (size_t)b * (KK * DD);
    const float* segb = seg + (size_t)b * DD;
    float* ofm = out_fm + (size_t)b * (RR * DD);
    float* ocm = out_cm + (size_t)b * (KK * DD);

    const int r0 = w, r1 = w + 4;

    // fm sources (wave-uniform selection)
    const float* f0src = shf ? fmb + (r0 + 1) * DD
                             : (ins && r0 == cnt) ? segb : fmb + r0 * DD;
    const float* f1src = shf ? ((r1 < 7) ? fmb + (r1 + 1) * DD : segb)
                             : (ins && r1 == cnt) ? segb : fmb + r1 * DD;
    // cm sources; shf && row==7 produced by inline conv below
    const bool   c1st  = !(shf && r1 == 7);
    const float* c0src = cmb + (shf ? r0 + 1 : r0) * DD;
    const float* c1src = c1st ? cmb + (shf ? r1 + 1 : r1) * DD : cmb;

    // issue all stream loads first (MLP=4) — nontemporal
    f4 a  = ntload(f0src + c);
    f4 bq = ntload(f1src + c);
    f4 d  = ntload(c0src + c);
    f4 e  = ntload(c1src + c);

    // nontemporal stores (write-once)
    ntstore(ofm + r0 * DD + c, a);
    ntstore(ofm + r1 * DD + c, bq);
    ntstore(ocm + r0 * DD + c, d);
    if (c1st) ntstore(ocm + r1 * DD + c, e);

    if (tid == 0)
        out_cnt[b] = (float)(cnt + (ins ? 1 : 0));

    if (shf) {                              // block-uniform; conv is per-wave
        f4 cv = *(const f4*)(cmb + (KK - 1) * DD + c);
        f4 fv = *(const f4*)(fmb + c);
        f4 x0 = {cv.x, fv.x, cv.y, fv.y};
        f4 x1 = {cv.z, fv.z, cv.w, fv.w};
        *(f4*)&xbuf[w][2 * c]     = x0;
        *(f4*)&xbuf[w][2 * c + 4] = x1;
        // wave-internal LDS dep -> compiler emits lgkmcnt wait; no __syncthreads

        const int o = (w << 6) + lane;      // wave w owns channels 64w..64w+63
        float acc = 0.f;
        const unsigned short* wp = Wt2b + o * 4;
        #pragma unroll 8
        for (int m4 = 0; m4 < 128; ++m4) {
            const ushort4 wq = *(const ushort4*)(wp + (size_t)m4 * (DD * 4)); // 512B/wave, L2-hot
            const f4 xq = *(const f4*)&xbuf[w][m4 * 4];                       // uniform -> broadcast
            acc += xq.x * bf2f(wq.x) + xq.y * bf2f(wq.y)
                 + xq.z * bf2f(wq.z) + xq.w * bf2f(wq.w);
        }
        acc += bias[o];
        ocm[(KK - 1) * DD + o] = acc;       // 256B/wave coalesced
    }
}

extern "C" void kernel_launch(void* const* d_in, const int* in_sizes, int n_in,
                              void* d_out, int out_size, void* d_ws, size_t ws_size,
                              hipStream_t stream) {
    const float* fm    = (const float*)d_in[0];
    const float* cm    = (const float*)d_in[1];
    const int*   cnt   = (const int*)d_in[2];
    const float* seg   = (const float*)d_in[3];
    const int*   valid = (const int*)d_in[4];
    const float* W     = (const float*)d_in[5];
    const float* bias  = (const float*)d_in[6];

    float* out_fm  = (float*)d_out;
    float* out_cm  = out_fm + (size_t)NB * RR * DD;
    float* out_cnt = out_cm + (size_t)NB * KK * DD;

    unsigned short* Wt2b = (unsigned short*)d_ws;   // 256KB

    hipLaunchKernelGGL(transpose_pack, dim3(WFLOATS / 256), dim3(256), 0, stream, W, Wt2b);
    hipLaunchKernelGGL(fused_update, dim3(NB), dim3(256), 0, stream,
                       fm, cm, cnt, seg, valid, Wt2b, bias, out_fm, out_cm, out_cnt);
}